// Round 1
// baseline (413.364 us; speedup 1.0000x reference)
//
#include <hip/hip_runtime.h>
#include <hip/hip_bf16.h>

// Problem constants
#define BB_   8
#define DIM_  512
#define LIN_  4096
#define LOUT_ 8192

typedef __attribute__((ext_vector_type(8))) __bf16 bf16x8;
typedef __attribute__((ext_vector_type(4))) float  f32x4;

__device__ __forceinline__ void async_copy16(const void* g, void* l) {
  __builtin_amdgcn_global_load_lds(
      (__attribute__((address_space(1))) void*)g,
      (__attribute__((address_space(3))) void*)l, 16, 0, 0);
}

// ---------------------------------------------------------------------------
// 1) transpose-cast: x[b][d][l] fp32 -> Xt[b][l][d] bf16  (K-contiguous B^T)
// grid (8, 8, 64), block 256
__global__ __launch_bounds__(256) void k_transpose(const float* __restrict__ x,
                                                   __hip_bfloat16* __restrict__ Xt) {
  __shared__ float t[64][65];
  const int b  = blockIdx.x;
  const int d0 = blockIdx.y * 64;
  const int l0 = blockIdx.z * 64;
  const int tid = threadIdx.x;
  const int jj = tid & 63;
  const int i0 = tid >> 6;
#pragma unroll
  for (int r = 0; r < 16; ++r) {
    const int i = i0 + r * 4;                      // d-local
    t[i][jj] = x[(size_t)(b * DIM_ + d0 + i) * LIN_ + l0 + jj];
  }
  __syncthreads();
#pragma unroll
  for (int r = 0; r < 16; ++r) {
    const int i = i0 + r * 4;                      // l-local
    Xt[(size_t)(b * LIN_ + l0 + i) * DIM_ + d0 + jj] = __float2bfloat16(t[jj][i]);
  }
}

// ---------------------------------------------------------------------------
// 2a) prep: Mstack[kk*512+e][i] = sum_d proj_w[e,d] * conv_w[d,i,kk]  (bf16 out)
// grid (3, 8, 8), block 256
__global__ __launch_bounds__(256) void k_prep(const float* __restrict__ proj_w,
                                              const float* __restrict__ conv_w,
                                              __hip_bfloat16* __restrict__ Mst) {
  const int kk = blockIdx.x;
  const int et = blockIdx.y * 64;
  const int it = blockIdx.z * 64;
  __shared__ float Pt[64][65];
  __shared__ float Wt[64][65];
  const int tid = threadIdx.x;
  const int tx = tid & 15, ty = tid >> 4;
  float acc[4][4] = {};
  for (int d0 = 0; d0 < DIM_; d0 += 64) {
#pragma unroll
    for (int r = 0; r < 4; ++r) {
      const int i = ty + r * 16;
      const int j = tx * 4;
      const float4 v = *(const float4*)&proj_w[(size_t)(et + i) * DIM_ + d0 + j];
      Pt[i][j] = v.x; Pt[i][j + 1] = v.y; Pt[i][j + 2] = v.z; Pt[i][j + 3] = v.w;
    }
#pragma unroll
    for (int r = 0; r < 16; ++r) {
      const int idx = tid + r * 256;
      const int i = idx >> 6, j = idx & 63;
      Wt[i][j] = conv_w[(size_t)(d0 + i) * (DIM_ * 3) + (it + j) * 3 + kk];
    }
    __syncthreads();
#pragma unroll
    for (int dl = 0; dl < 64; ++dl) {
      float pv[4], wv[4];
#pragma unroll
      for (int a = 0; a < 4; ++a) pv[a] = Pt[ty * 4 + a][dl];
#pragma unroll
      for (int bq = 0; bq < 4; ++bq) wv[bq] = Wt[dl][tx * 4 + bq];
#pragma unroll
      for (int a = 0; a < 4; ++a)
#pragma unroll
        for (int bq = 0; bq < 4; ++bq) acc[a][bq] += pv[a] * wv[bq];
    }
    __syncthreads();
  }
#pragma unroll
  for (int a = 0; a < 4; ++a)
#pragma unroll
    for (int bq = 0; bq < 4; ++bq)
      Mst[(size_t)(kk * DIM_ + et + ty * 4 + a) * DIM_ + it + tx * 4 + bq] =
          __float2bfloat16(acc[a][bq]);
}

// 2b) Pcb[e] = sum_d proj_w[e,d] * conv_b[d].  grid 512, block 64
__global__ __launch_bounds__(64) void k_pcb(const float* __restrict__ proj_w,
                                            const float* __restrict__ conv_b,
                                            float* __restrict__ Pcb) {
  const int e = blockIdx.x;
  const int j = threadIdx.x;
  float s = 0.f;
#pragma unroll
  for (int d = j; d < DIM_; d += 64) s += proj_w[(size_t)e * DIM_ + d] * conv_b[d];
#pragma unroll
  for (int off = 32; off > 0; off >>= 1) s += __shfl_down(s, off, 64);
  if (j == 0) Pcb[e] = s;
}

// ---------------------------------------------------------------------------
// 3) GEMM: U[row=kk*512+e][col=b*4096+l] = Mstack[row,:] . Xt[col,:]  (K=512)
//    + Pcb[e] on planes kk=0,1.  Stored as U[kk][b][e][l] bf16.
// grid (12, 256), block 256 (4 waves, 128x128 tile, BK=32)
__global__ __launch_bounds__(256) void k_gemm(const __hip_bfloat16* __restrict__ A,
                                              const __hip_bfloat16* __restrict__ Bt,
                                              const float* __restrict__ Pcb,
                                              __hip_bfloat16* __restrict__ U) {
  __shared__ __align__(16) __hip_bfloat16 As[128 * 32];
  __shared__ __align__(16) __hip_bfloat16 Bs[128 * 32];
  const int tid = threadIdx.x;
  const int r0 = blockIdx.x * 128;
  const int c0 = blockIdx.y * 128;
  const int lane = tid & 63;
  const int wave = tid >> 6;
  const int wm = wave >> 1, wn = wave & 1;

  const __hip_bfloat16* a0 = A + (size_t)(r0 + (tid >> 2)) * 512 + (tid & 3) * 8;
  const __hip_bfloat16* a1 = a0 + (size_t)64 * 512;
  const __hip_bfloat16* b0 = Bt + (size_t)(c0 + (tid >> 2)) * 512 + (tid & 3) * 8;
  const __hip_bfloat16* b1 = b0 + (size_t)64 * 512;
  __hip_bfloat16* lA0 = As + tid * 8;
  __hip_bfloat16* lA1 = As + (tid + 256) * 8;
  __hip_bfloat16* lB0 = Bs + tid * 8;
  __hip_bfloat16* lB1 = Bs + (tid + 256) * 8;

  f32x4 acc[4][4] = {};

  const int klo  = (lane >> 4) * 8;
  const int mrow = wm * 64 + (lane & 15);
  const int ncol = wn * 64 + (lane & 15);

  for (int kt = 0; kt < 512; kt += 32) {
    async_copy16(a0 + kt, lA0);
    async_copy16(a1 + kt, lA1);
    async_copy16(b0 + kt, lB0);
    async_copy16(b1 + kt, lB1);
    __syncthreads();   // drains vmcnt for global_load_lds (m97 structure)
    bf16x8 af[4], bfr[4];
#pragma unroll
    for (int i = 0; i < 4; ++i)
      af[i] = *(const bf16x8*)(As + (mrow + i * 16) * 32 + klo);
#pragma unroll
    for (int i = 0; i < 4; ++i)
      bfr[i] = *(const bf16x8*)(Bs + (ncol + i * 16) * 32 + klo);
#pragma unroll
    for (int mt = 0; mt < 4; ++mt)
#pragma unroll
      for (int nt = 0; nt < 4; ++nt)
        acc[mt][nt] = __builtin_amdgcn_mfma_f32_16x16x32_bf16(af[mt], bfr[nt],
                                                              acc[mt][nt], 0, 0, 0);
    __syncthreads();
  }

  const int kk = r0 >> 9;            // plane (128 divides 512, uniform per block)
  const int bb = c0 >> 12;           // batch (128 divides 4096)
  const int e0 = (r0 & 511) + wm * 64;
  const int l0 = (c0 & 4095) + wn * 64;
#pragma unroll
  for (int mt = 0; mt < 4; ++mt) {
#pragma unroll
    for (int nt = 0; nt < 4; ++nt) {
      const int ltile = l0 + nt * 16 + (lane & 15);           // D: col = lane&15
      const int ebase = e0 + mt * 16 + (lane >> 4) * 4;       // D: row = quad*4+reg
#pragma unroll
      for (int r = 0; r < 4; ++r) {
        float v = acc[mt][nt][r];
        const int e = ebase + r;
        if (kk < 2) v += Pcb[e];     // bias once: via plane 1 (even) / plane 0 (odd)
        U[(size_t)((kk * 8 + bb) * 512 + e) * 4096 + ltile] = __float2bfloat16(v);
      }
    }
  }
}

// ---------------------------------------------------------------------------
// 4) AA filter + proj bias.
//    u_even(l) = U1[l];  u_odd(l) = U0[l] + U2[l+1] (l+1==4096 -> 0)
//    out[t] = sum_j aa[j] * u[t+j-8] + proj_b[e]   (zero-pad u outside [0,8192))
// grid (4096, 4), block 256
__global__ __launch_bounds__(256) void k_aa(const __hip_bfloat16* __restrict__ U,
                                            const float* __restrict__ aa,
                                            const float* __restrict__ proj_b,
                                            float* __restrict__ out) {
  const int b  = blockIdx.x >> 9;
  const int e  = blockIdx.x & 511;
  const int l0 = blockIdx.y << 10;
  __shared__ float ue[1040];
  __shared__ float uo[1040];
  __shared__ float sa[17];
  const int tid = threadIdx.x;
  if (tid < 17) sa[tid] = aa[tid];
  const __hip_bfloat16* U0 = U + (size_t)((0 * 8 + b) * 512 + e) * 4096;
  const __hip_bfloat16* U1 = U + (size_t)((1 * 8 + b) * 512 + e) * 4096;
  const __hip_bfloat16* U2 = U + (size_t)((2 * 8 + b) * 512 + e) * 4096;
  for (int s = tid; s < 1040; s += 256) {
    const int l = l0 - 8 + s;
    float ve = 0.f, vo = 0.f;
    if (l >= 0 && l < 4096) {
      ve = __bfloat162float(U1[l]);
      vo = __bfloat162float(U0[l]);
      if (l + 1 < 4096) vo += __bfloat162float(U2[l + 1]);
    }
    ue[s] = ve;
    uo[s] = vo;
  }
  __syncthreads();
  const float pb = proj_b[e];
  float* orow = out + (size_t)(b * 512 + e) * 8192;
#pragma unroll
  for (int r = 0; r < 4; ++r) {
    const int li = tid + r * 256;    // 0..1023
    const int s  = li + 8;
    float se = 0.f, so = 0.f;
#pragma unroll
    for (int q = 0; q <= 8; ++q) {   // even taps j=2q
      se += sa[2 * q] * ue[s + q - 4];
      so += sa[2 * q] * uo[s + q - 4];
    }
#pragma unroll
    for (int q = 0; q < 8; ++q) {    // odd taps j=2q+1
      se += sa[2 * q + 1] * uo[s + q - 4];
      so += sa[2 * q + 1] * ue[s + q - 3];
    }
    float2 v;
    v.x = se + pb;
    v.y = so + pb;
    *(float2*)(orow + 2 * (l0 + li)) = v;
  }
}

// ---------------------------------------------------------------------------
extern "C" void kernel_launch(void* const* d_in, const int* in_sizes, int n_in,
                              void* d_out, int out_size, void* d_ws, size_t ws_size,
                              hipStream_t stream) {
  const float* x      = (const float*)d_in[0];
  const float* conv_w = (const float*)d_in[1];
  const float* conv_b = (const float*)d_in[2];
  const float* aa     = (const float*)d_in[3];
  const float* proj_w = (const float*)d_in[4];
  const float* proj_b = (const float*)d_in[5];
  float* out = (float*)d_out;

  char* ws = (char*)d_ws;
  __hip_bfloat16* Xt  = (__hip_bfloat16*)ws;                    // 33,554,432 B
  __hip_bfloat16* Mst = (__hip_bfloat16*)(ws + 33554432);       //  1,572,864 B
  float*          Pcb = (float*)(ws + 35127296);                //      2,048 B
  __hip_bfloat16* U   = (__hip_bfloat16*)(ws + 35129344);       // 100,663,296 B

  k_transpose<<<dim3(8, 8, 64), 256, 0, stream>>>(x, Xt);
  k_prep<<<dim3(3, 8, 8), 256, 0, stream>>>(proj_w, conv_w, Mst);
  k_pcb<<<dim3(512, 1, 1), 64, 0, stream>>>(proj_w, conv_b, Pcb);
  k_gemm<<<dim3(12, 256), 256, 0, stream>>>(Mst, Xt, Pcb, U);
  k_aa<<<dim3(4096, 4), 256, 0, stream>>>(U, aa, proj_b, out);
}

// Round 2
// 384.517 us; speedup vs baseline: 1.0750x; 1.0750x over previous
//
#include <hip/hip_runtime.h>
#include <hip/hip_bf16.h>

// Problem constants
#define BB_   8
#define DIM_  512
#define LIN_  4096
#define LOUT_ 8192

typedef __attribute__((ext_vector_type(8))) __bf16 bf16x8;
typedef __attribute__((ext_vector_type(4))) float  f32x4;

__device__ __forceinline__ void async_copy16(const void* g, void* l) {
  __builtin_amdgcn_global_load_lds(
      (__attribute__((address_space(1))) void*)g,
      (__attribute__((address_space(3))) void*)l, 16, 0, 0);
}

// ---------------------------------------------------------------------------
// 1) transpose-cast: x[b][d][l] fp32 -> Xt[b][l][d] bf16  (K-contiguous B^T)
// grid (8, 8, 64), block 256
__global__ __launch_bounds__(256) void k_transpose(const float* __restrict__ x,
                                                   __hip_bfloat16* __restrict__ Xt) {
  __shared__ float t[64][65];
  const int b  = blockIdx.x;
  const int d0 = blockIdx.y * 64;
  const int l0 = blockIdx.z * 64;
  const int tid = threadIdx.x;
  const int jj = tid & 63;
  const int i0 = tid >> 6;
#pragma unroll
  for (int r = 0; r < 16; ++r) {
    const int i = i0 + r * 4;                      // d-local
    t[i][jj] = x[(size_t)(b * DIM_ + d0 + i) * LIN_ + l0 + jj];
  }
  __syncthreads();
#pragma unroll
  for (int r = 0; r < 16; ++r) {
    const int i = i0 + r * 4;                      // l-local
    Xt[(size_t)(b * LIN_ + l0 + i) * DIM_ + d0 + jj] = __float2bfloat16(t[jj][i]);
  }
}

// ---------------------------------------------------------------------------
// 2a) prep: Mstack[kk*512+e][i] = sum_d proj_w[e,d] * conv_w[d,i,kk]  (bf16 out)
// 32x32 tiles for parallelism: grid (3, 16, 16) = 768 blocks, block 256
__global__ __launch_bounds__(256) void k_prep(const float* __restrict__ proj_w,
                                              const float* __restrict__ conv_w,
                                              __hip_bfloat16* __restrict__ Mst) {
  const int kk = blockIdx.x;
  const int et = blockIdx.y * 32;
  const int it = blockIdx.z * 32;
  __shared__ float Pt[32][33];
  __shared__ float Wt[32][33];
  const int tid = threadIdx.x;
  const int tx = tid & 15, ty = tid >> 4;
  float acc[2][2] = {};
  for (int d0 = 0; d0 < DIM_; d0 += 32) {
    {  // Pt[e-local][d-local], float4 loads: 32x32 = 256 threads x 4
      const int i = tid >> 3;
      const int j = (tid & 7) * 4;
      const float4 v = *(const float4*)&proj_w[(size_t)(et + i) * DIM_ + d0 + j];
      Pt[i][j] = v.x; Pt[i][j + 1] = v.y; Pt[i][j + 2] = v.z; Pt[i][j + 3] = v.w;
    }
#pragma unroll
    for (int r = 0; r < 4; ++r) {  // Wt[d-local][i-local]
      const int idx = tid + r * 256;
      const int i = idx >> 5, j = idx & 31;
      Wt[i][j] = conv_w[(size_t)(d0 + i) * (DIM_ * 3) + (it + j) * 3 + kk];
    }
    __syncthreads();
#pragma unroll
    for (int dl = 0; dl < 32; ++dl) {
      float pv[2], wv[2];
      pv[0] = Pt[ty * 2][dl];     pv[1] = Pt[ty * 2 + 1][dl];
      wv[0] = Wt[dl][tx * 2];     wv[1] = Wt[dl][tx * 2 + 1];
#pragma unroll
      for (int a = 0; a < 2; ++a)
#pragma unroll
        for (int bq = 0; bq < 2; ++bq) acc[a][bq] += pv[a] * wv[bq];
    }
    __syncthreads();
  }
#pragma unroll
  for (int a = 0; a < 2; ++a)
#pragma unroll
    for (int bq = 0; bq < 2; ++bq)
      Mst[(size_t)(kk * DIM_ + et + ty * 2 + a) * DIM_ + it + tx * 2 + bq] =
          __float2bfloat16(acc[a][bq]);
}

// 2b) Pcb[e] = sum_d proj_w[e,d] * conv_b[d].  grid 512, block 64
__global__ __launch_bounds__(64) void k_pcb(const float* __restrict__ proj_w,
                                            const float* __restrict__ conv_b,
                                            float* __restrict__ Pcb) {
  const int e = blockIdx.x;
  const int j = threadIdx.x;
  float s = 0.f;
#pragma unroll
  for (int d = j; d < DIM_; d += 64) s += proj_w[(size_t)e * DIM_ + d] * conv_b[d];
#pragma unroll
  for (int off = 32; off > 0; off >>= 1) s += __shfl_down(s, off, 64);
  if (j == 0) Pcb[e] = s;
}

// ---------------------------------------------------------------------------
// 3) GEMM: U[row=kk*512+e][col=b*4096+l] = Mstack[row,:] . Xt[col,:]  (K=512)
//    + Pcb[e] on planes kk=0,1.  Stored as U[kk][b][e][l] bf16.
// BK=64 (2 MFMA K-steps per barrier pair, 8 iterations), XOR-swizzled LDS so
// the 128B row stride doesn't serialize ds_read_b128.
// grid (12, 256), block 256 (4 waves, 128x128 tile)
__global__ __launch_bounds__(256) void k_gemm(const __hip_bfloat16* __restrict__ A,
                                              const __hip_bfloat16* __restrict__ Bt,
                                              const float* __restrict__ Pcb,
                                              __hip_bfloat16* __restrict__ U) {
  __shared__ __align__(16) __hip_bfloat16 As[128 * 64];
  __shared__ __align__(16) __hip_bfloat16 Bs[128 * 64];
  const int tid = threadIdx.x;
  const int r0 = blockIdx.x * 128;
  const int c0 = blockIdx.y * 128;
  const int lane = tid & 63;
  const int wave = tid >> 6;
  const int wm = wave >> 1, wn = wave & 1;

  // staging: thread t fills LDS 16B-chunk t (+256/it); global chunk XOR-permuted
  // per row so fragment reads land on distinct banks.
  const int srow = tid >> 3;                       // 0..31
  const int cg   = (tid & 7) ^ (srow & 7);         // global k-chunk for this slot
  const __hip_bfloat16* aptr = A  + (size_t)(r0 + srow) * 512 + cg * 8;
  const __hip_bfloat16* bptr = Bt + (size_t)(c0 + srow) * 512 + cg * 8;
  __hip_bfloat16* ldsA = As + tid * 8;
  __hip_bfloat16* ldsB = Bs + tid * 8;

  f32x4 acc[4][4] = {};

  const int kq   = lane >> 4;                      // k-group 0..3 (x8 elems)
  const int mrow = wm * 64 + (lane & 15);
  const int ncol = wn * 64 + (lane & 15);

  for (int kt = 0; kt < 512; kt += 64) {
#pragma unroll
    for (int it = 0; it < 4; ++it) {
      async_copy16(aptr + (size_t)(it * 32) * 512 + kt, ldsA + it * 2048);
      async_copy16(bptr + (size_t)(it * 32) * 512 + kt, ldsB + it * 2048);
    }
    __syncthreads();
#pragma unroll
    for (int k0 = 0; k0 < 64; k0 += 32) {
      const int c = (k0 >> 3) + kq;                // k-chunk 0..7
      bf16x8 af[4], bfr[4];
#pragma unroll
      for (int i = 0; i < 4; ++i) {
        const int rg = mrow + i * 16;
        af[i] = *(const bf16x8*)(As + rg * 64 + ((c ^ (rg & 7)) * 8));
      }
#pragma unroll
      for (int i = 0; i < 4; ++i) {
        const int rg = ncol + i * 16;
        bfr[i] = *(const bf16x8*)(Bs + rg * 64 + ((c ^ (rg & 7)) * 8));
      }
#pragma unroll
      for (int mt = 0; mt < 4; ++mt)
#pragma unroll
        for (int nt = 0; nt < 4; ++nt)
          acc[mt][nt] = __builtin_amdgcn_mfma_f32_16x16x32_bf16(af[mt], bfr[nt],
                                                                acc[mt][nt], 0, 0, 0);
    }
    __syncthreads();
  }

  const int kk = r0 >> 9;            // plane (128 divides 512, uniform per block)
  const int bb = c0 >> 12;           // batch (128 divides 4096)
  const int e0 = (r0 & 511) + wm * 64;
  const int l0 = (c0 & 4095) + wn * 64;
#pragma unroll
  for (int mt = 0; mt < 4; ++mt) {
#pragma unroll
    for (int nt = 0; nt < 4; ++nt) {
      const int ltile = l0 + nt * 16 + (lane & 15);           // D: col = lane&15
      const int ebase = e0 + mt * 16 + (lane >> 4) * 4;       // D: row = quad*4+reg
#pragma unroll
      for (int r = 0; r < 4; ++r) {
        float v = acc[mt][nt][r];
        const int e = ebase + r;
        if (kk < 2) v += Pcb[e];     // bias once: via plane 1 (even) / plane 0 (odd)
        U[(size_t)((kk * 8 + bb) * 512 + e) * 4096 + ltile] = __float2bfloat16(v);
      }
    }
  }
}

// ---------------------------------------------------------------------------
// 4) AA filter + proj bias.
//    u_even(l) = U1[l];  u_odd(l) = U0[l] + U2[l+1] (l+1==4096 -> 0)
//    out[t] = sum_j aa[j] * u[t+j-8] + proj_b[e]   (zero-pad u outside [0,8192))
// Each thread: 4 consecutive output pairs; windows via 3+3 ds_read_b128;
// 2 coalesced float4 stores. grid (4096, 4), block 256
__global__ __launch_bounds__(256) void k_aa(const __hip_bfloat16* __restrict__ U,
                                            const float* __restrict__ aa,
                                            const float* __restrict__ proj_b,
                                            float* __restrict__ out) {
  const int b  = blockIdx.x >> 9;
  const int e  = blockIdx.x & 511;
  const int l0 = blockIdx.y << 10;
  __shared__ __align__(16) float ue[1040];
  __shared__ __align__(16) float uo[1040];
  __shared__ float sa[17];
  const int tid = threadIdx.x;
  if (tid < 17) sa[tid] = aa[tid];
  const __hip_bfloat16* U0 = U + (size_t)((0 * 8 + b) * 512 + e) * 4096;
  const __hip_bfloat16* U1 = U + (size_t)((1 * 8 + b) * 512 + e) * 4096;
  const __hip_bfloat16* U2 = U + (size_t)((2 * 8 + b) * 512 + e) * 4096;
  for (int s = tid; s < 1040; s += 256) {
    const int l = l0 - 8 + s;
    float ve = 0.f, vo = 0.f;
    if (l >= 0 && l < 4096) {
      ve = __bfloat162float(U1[l]);
      vo = __bfloat162float(U0[l]);
      if (l + 1 < 4096) vo += __bfloat162float(U2[l + 1]);
    }
    ue[s] = ve;
    uo[s] = vo;
  }
  __syncthreads();
  const float pb = proj_b[e];
  const int li0 = tid * 4;           // 4 consecutive output pairs
  const int w0  = li0 + 4;           // = (li0+8) - 4, 16B-aligned index
  float Ew[12], Ow[12];
#pragma unroll
  for (int c = 0; c < 3; ++c) {
    const float4 ve = *(const float4*)&ue[w0 + 4 * c];
    const float4 vo = *(const float4*)&uo[w0 + 4 * c];
    Ew[4 * c] = ve.x; Ew[4 * c + 1] = ve.y; Ew[4 * c + 2] = ve.z; Ew[4 * c + 3] = ve.w;
    Ow[4 * c] = vo.x; Ow[4 * c + 1] = vo.y; Ow[4 * c + 2] = vo.z; Ow[4 * c + 3] = vo.w;
  }
  float res[8];
#pragma unroll
  for (int t = 0; t < 4; ++t) {
    float se = 0.f, so = 0.f;
#pragma unroll
    for (int q = 0; q <= 8; ++q) {   // even taps j=2q
      se += sa[2 * q] * Ew[t + q];
      so += sa[2 * q] * Ow[t + q];
    }
#pragma unroll
    for (int q = 0; q < 8; ++q) {    // odd taps j=2q+1
      se += sa[2 * q + 1] * Ow[t + q];
      so += sa[2 * q + 1] * Ew[t + q + 1];
    }
    res[2 * t]     = se + pb;
    res[2 * t + 1] = so + pb;
  }
  float* orow = out + (size_t)(b * 512 + e) * 8192 + 2 * (l0 + li0);
  *(float4*)(orow)     = *(float4*)&res[0];
  *(float4*)(orow + 4) = *(float4*)&res[4];
}

// ---------------------------------------------------------------------------
extern "C" void kernel_launch(void* const* d_in, const int* in_sizes, int n_in,
                              void* d_out, int out_size, void* d_ws, size_t ws_size,
                              hipStream_t stream) {
  const float* x      = (const float*)d_in[0];
  const float* conv_w = (const float*)d_in[1];
  const float* conv_b = (const float*)d_in[2];
  const float* aa     = (const float*)d_in[3];
  const float* proj_w = (const float*)d_in[4];
  const float* proj_b = (const float*)d_in[5];
  float* out = (float*)d_out;

  char* ws = (char*)d_ws;
  __hip_bfloat16* Xt  = (__hip_bfloat16*)ws;                    // 33,554,432 B
  __hip_bfloat16* Mst = (__hip_bfloat16*)(ws + 33554432);       //  1,572,864 B
  float*          Pcb = (float*)(ws + 35127296);                //      2,048 B
  __hip_bfloat16* U   = (__hip_bfloat16*)(ws + 35129344);       // 100,663,296 B

  k_transpose<<<dim3(8, 8, 64), 256, 0, stream>>>(x, Xt);
  k_prep<<<dim3(3, 16, 16), 256, 0, stream>>>(proj_w, conv_w, Mst);
  k_pcb<<<dim3(512, 1, 1), 64, 0, stream>>>(proj_w, conv_b, Pcb);
  k_gemm<<<dim3(12, 256), 256, 0, stream>>>(Mst, Xt, Pcb, U);
  k_aa<<<dim3(4096, 4), 256, 0, stream>>>(U, aa, proj_b, out);
}

// Round 3
// 380.701 us; speedup vs baseline: 1.0858x; 1.0100x over previous
//
#include <hip/hip_runtime.h>
#include <hip/hip_bf16.h>

// Problem constants
#define BB_   8
#define DIM_  512
#define LIN_  4096
#define LOUT_ 8192

typedef __attribute__((ext_vector_type(8))) __bf16 bf16x8;
typedef __attribute__((ext_vector_type(4))) float  f32x4;

__device__ __forceinline__ float bf2f(unsigned short u) {
  union { unsigned int i; float f; } x;
  x.i = ((unsigned int)u) << 16;
  return x.f;
}

// ---------------------------------------------------------------------------
// 1) Fused prologue kernel: heterogeneous grid, 4992 blocks of 256.
//    [0,4096):   transpose-cast x[b][d][l] fp32 -> Xt[b][l][d] bf16
//    [4096,4864): Mstack[kk*512+e][i] = sum_d proj_w[e,d]*conv_w[d,i,kk] (bf16)
//    [4864,4992): Pcb[e] = sum_d proj_w[e,d]*conv_b[d]
__global__ __launch_bounds__(256) void k_pre(const float* __restrict__ x,
                                             const float* __restrict__ proj_w,
                                             const float* __restrict__ conv_w,
                                             const float* __restrict__ conv_b,
                                             __hip_bfloat16* __restrict__ Xt,
                                             __hip_bfloat16* __restrict__ Mst,
                                             float* __restrict__ Pcb) {
  __shared__ float smem[64 * 65];
  const int bx  = blockIdx.x;
  const int tid = threadIdx.x;
  if (bx < 4096) {
    // ---- transpose ----
    const int b  = bx & 7;
    const int d0 = ((bx >> 3) & 7) * 64;
    const int l0 = (bx >> 6) * 64;
    const int jj = tid & 63;
    const int i0 = tid >> 6;
#pragma unroll
    for (int r = 0; r < 16; ++r) {
      const int i = i0 + r * 4;                    // d-local
      smem[i * 65 + jj] = x[(size_t)(b * DIM_ + d0 + i) * LIN_ + l0 + jj];
    }
    __syncthreads();
#pragma unroll
    for (int r = 0; r < 16; ++r) {
      const int i = i0 + r * 4;                    // l-local
      Xt[(size_t)(b * LIN_ + l0 + i) * DIM_ + d0 + jj] =
          __float2bfloat16(smem[jj * 65 + i]);
    }
  } else if (bx < 4864) {
    // ---- prep: 3 x 16 x 16 tiles of 32x32 ----
    const int idx = bx - 4096;
    const int kk = idx >> 8;
    const int et = ((idx >> 4) & 15) * 32;
    const int it = (idx & 15) * 32;
    float* Pt = smem;              // [32][33]
    float* Wt = smem + 32 * 33;    // [32][33]
    const int tx = tid & 15, ty = tid >> 4;
    float acc[2][2] = {};
    for (int d0 = 0; d0 < DIM_; d0 += 32) {
      {
        const int i = tid >> 3;
        const int j = (tid & 7) * 4;
        const float4 v = *(const float4*)&proj_w[(size_t)(et + i) * DIM_ + d0 + j];
        Pt[i * 33 + j] = v.x; Pt[i * 33 + j + 1] = v.y;
        Pt[i * 33 + j + 2] = v.z; Pt[i * 33 + j + 3] = v.w;
      }
#pragma unroll
      for (int r = 0; r < 4; ++r) {
        const int id2 = tid + r * 256;
        const int i = id2 >> 5, j = id2 & 31;
        Wt[i * 33 + j] = conv_w[(size_t)(d0 + i) * (DIM_ * 3) + (it + j) * 3 + kk];
      }
      __syncthreads();
#pragma unroll
      for (int dl = 0; dl < 32; ++dl) {
        float pv[2], wv[2];
        pv[0] = Pt[(ty * 2) * 33 + dl];     pv[1] = Pt[(ty * 2 + 1) * 33 + dl];
        wv[0] = Wt[dl * 33 + tx * 2];       wv[1] = Wt[dl * 33 + tx * 2 + 1];
#pragma unroll
        for (int a = 0; a < 2; ++a)
#pragma unroll
          for (int bq = 0; bq < 2; ++bq) acc[a][bq] += pv[a] * wv[bq];
      }
      __syncthreads();
    }
#pragma unroll
    for (int a = 0; a < 2; ++a)
#pragma unroll
      for (int bq = 0; bq < 2; ++bq)
        Mst[(size_t)(kk * DIM_ + et + ty * 2 + a) * DIM_ + it + tx * 2 + bq] =
            __float2bfloat16(acc[a][bq]);
  } else {
    // ---- Pcb: 128 blocks x 4 e-rows (one wave each) ----
    const int idx = bx - 4864;
    const int e = idx * 4 + (tid >> 6);
    const int j = tid & 63;
    float s = 0.f;
#pragma unroll
    for (int d = j; d < DIM_; d += 64) s += proj_w[(size_t)e * DIM_ + d] * conv_b[d];
#pragma unroll
    for (int off = 32; off > 0; off >>= 1) s += __shfl_down(s, off, 64);
    if (j == 0) Pcb[e] = s;
  }
}

// ---------------------------------------------------------------------------
// 2) GEMM: U[row=kk*512+e][col=b*4096+l] = Mstack[row,:] . Xt[col,:]  (K=512)
//    + Pcb[e] on planes kk=0,1.  Stored as U[kk][b][e][l] bf16.
// Pipelined: register prefetch of tile kt+1 in flight across tile kt's 64 MFMA,
// LDS double-buffer (2x32KB), ONE barrier per K-iter. XOR-swizzled LDS rows.
// grid (12, 256), block 256 (4 waves, 128x128 tile, BK=64)
__global__ __launch_bounds__(256, 2) void k_gemm(const __hip_bfloat16* __restrict__ A,
                                                 const __hip_bfloat16* __restrict__ Bt,
                                                 const float* __restrict__ Pcb,
                                                 __hip_bfloat16* __restrict__ U) {
  __shared__ __align__(16) __hip_bfloat16 As[2][128 * 64];
  __shared__ __align__(16) __hip_bfloat16 Bs[2][128 * 64];
  const int tid = threadIdx.x;
  const int r0 = blockIdx.x * 128;
  const int c0 = blockIdx.y * 128;
  const int lane = tid & 63;
  const int wave = tid >> 6;
  const int wm = wave >> 1, wn = wave & 1;

  // global->reg staging map: pass i covers rows rA+32i; 8 threads/row,
  // thread covers 16B chunk ch. LDS slot for (row rg, chunk ch) = ch ^ (rg&7).
  const int rA = tid >> 3;                         // 0..31
  const int ch = tid & 7;
  const __hip_bfloat16* aG = A  + (size_t)(r0 + rA) * 512 + ch * 8;
  const __hip_bfloat16* bG = Bt + (size_t)(c0 + rA) * 512 + ch * 8;
  int wo[4];
#pragma unroll
  for (int i = 0; i < 4; ++i) {
    const int rg = rA + 32 * i;
    wo[i] = rg * 64 + ((ch ^ (rg & 7)) * 8);
  }

  bf16x8 gA[4], gB[4];
#pragma unroll
  for (int i = 0; i < 4; ++i) {
    gA[i] = *(const bf16x8*)(aG + (size_t)(32 * i) * 512);
    gB[i] = *(const bf16x8*)(bG + (size_t)(32 * i) * 512);
  }
#pragma unroll
  for (int i = 0; i < 4; ++i) {
    *(bf16x8*)(&As[0][wo[i]]) = gA[i];
    *(bf16x8*)(&Bs[0][wo[i]]) = gB[i];
  }
  __syncthreads();

  f32x4 acc[4][4] = {};
  const int kq   = lane >> 4;
  const int mrow = wm * 64 + (lane & 15);
  const int ncol = wn * 64 + (lane & 15);

  for (int kt = 0; kt < 8; ++kt) {
    if (kt < 7) {                                   // prefetch next tile -> regs
#pragma unroll
      for (int i = 0; i < 4; ++i) {
        gA[i] = *(const bf16x8*)(aG + (size_t)(32 * i) * 512 + (kt + 1) * 64);
        gB[i] = *(const bf16x8*)(bG + (size_t)(32 * i) * 512 + (kt + 1) * 64);
      }
    }
    const __hip_bfloat16* Ab = As[kt & 1];
    const __hip_bfloat16* Bb = Bs[kt & 1];
#pragma unroll
    for (int k0 = 0; k0 < 64; k0 += 32) {
      const int c = (k0 >> 3) + kq;
      bf16x8 af[4], bfr[4];
#pragma unroll
      for (int i = 0; i < 4; ++i) {
        const int rg = mrow + i * 16;
        af[i] = *(const bf16x8*)(Ab + rg * 64 + ((c ^ (rg & 7)) * 8));
      }
#pragma unroll
      for (int i = 0; i < 4; ++i) {
        const int rg = ncol + i * 16;
        bfr[i] = *(const bf16x8*)(Bb + rg * 64 + ((c ^ (rg & 7)) * 8));
      }
#pragma unroll
      for (int mt = 0; mt < 4; ++mt)
#pragma unroll
        for (int nt = 0; nt < 4; ++nt)
          acc[mt][nt] = __builtin_amdgcn_mfma_f32_16x16x32_bf16(af[mt], bfr[nt],
                                                                acc[mt][nt], 0, 0, 0);
    }
    if (kt < 7) {                                   // write next tile to other buf
      __hip_bfloat16* wA = &As[(kt + 1) & 1][0];
      __hip_bfloat16* wB = &Bs[(kt + 1) & 1][0];
#pragma unroll
      for (int i = 0; i < 4; ++i) {
        *(bf16x8*)(&wA[wo[i]]) = gA[i];
        *(bf16x8*)(&wB[wo[i]]) = gB[i];
      }
    }
    __syncthreads();
  }

  const int kk = r0 >> 9;            // plane (uniform per block)
  const int bb = c0 >> 12;           // batch
  const int e0 = (r0 & 511) + wm * 64;
  const int l0 = (c0 & 4095) + wn * 64;
#pragma unroll
  for (int mt = 0; mt < 4; ++mt) {
#pragma unroll
    for (int nt = 0; nt < 4; ++nt) {
      const int ltile = l0 + nt * 16 + (lane & 15);           // D: col = lane&15
      const int ebase = e0 + mt * 16 + (lane >> 4) * 4;       // D: row = quad*4+reg
#pragma unroll
      for (int r = 0; r < 4; ++r) {
        float v = acc[mt][nt][r];
        const int e = ebase + r;
        if (kk < 2) v += Pcb[e];     // bias exactly once across planes
        U[(size_t)((kk * 8 + bb) * 512 + e) * 4096 + ltile] = __float2bfloat16(v);
      }
    }
  }
}

// ---------------------------------------------------------------------------
// 3) AA filter + proj bias, barrier-free.
//    u_even(l) = U1[l];  u_odd(l) = U0[l] + U2[l+1] (zero-pad outside [0,4096))
//    out[2l+p] = 17-tap AA over u + proj_b[e]
// Thread handles 4 consecutive output pairs; window [w, w+12) in l-domain via
// coalesced 8B vector loads (neighbor overlap served by L1). grid (4096, 4)
__global__ __launch_bounds__(256) void k_aa(const __hip_bfloat16* __restrict__ U,
                                            const float* __restrict__ aa,
                                            const float* __restrict__ proj_b,
                                            float* __restrict__ out) {
  const int b  = blockIdx.x >> 9;
  const int e  = blockIdx.x & 511;
  const int l0 = blockIdx.y << 10;
  const int tid = threadIdx.x;
  const int lt = l0 + 4 * tid;       // first l of this thread
  const int w  = lt - 4;             // window start
  const unsigned short* q0 = (const unsigned short*)(U + (size_t)((0 * 8 + b) * 512 + e) * 4096);
  const unsigned short* q1 = (const unsigned short*)(U + (size_t)((1 * 8 + b) * 512 + e) * 4096);
  const unsigned short* q2 = (const unsigned short*)(U + (size_t)((2 * 8 + b) * 512 + e) * 4096);

  float Ew[12], Ow[12];
  if (w >= 0 && w + 16 <= 4096) {
    unsigned short e1[12], e0a[12], e2[16];
#pragma unroll
    for (int c = 0; c < 3; ++c) {
      const ushort4 a = *(const ushort4*)(q1 + w + 4 * c);
      e1[4 * c] = a.x; e1[4 * c + 1] = a.y; e1[4 * c + 2] = a.z; e1[4 * c + 3] = a.w;
      const ushort4 d = *(const ushort4*)(q0 + w + 4 * c);
      e0a[4 * c] = d.x; e0a[4 * c + 1] = d.y; e0a[4 * c + 2] = d.z; e0a[4 * c + 3] = d.w;
    }
#pragma unroll
    for (int c = 0; c < 4; ++c) {
      const ushort4 a = *(const ushort4*)(q2 + w + 4 * c);
      e2[4 * c] = a.x; e2[4 * c + 1] = a.y; e2[4 * c + 2] = a.z; e2[4 * c + 3] = a.w;
    }
#pragma unroll
    for (int j = 0; j < 12; ++j) {
      Ew[j] = bf2f(e1[j]);
      Ow[j] = bf2f(e0a[j]) + bf2f(e2[j + 1]);
    }
  } else {
#pragma unroll
    for (int j = 0; j < 12; ++j) {
      const int l = w + j;
      float vE = 0.f, vO = 0.f;
      if (l >= 0 && l < 4096) {
        vE = bf2f(q1[l]);
        vO = bf2f(q0[l]);
        if (l + 1 < 4096) vO += bf2f(q2[l + 1]);
      }
      Ew[j] = vE; Ow[j] = vO;
    }
  }

  float sa[17];
#pragma unroll
  for (int j = 0; j < 17; ++j) sa[j] = aa[j];
  const float pb = proj_b[e];
  float res[8];
#pragma unroll
  for (int t = 0; t < 4; ++t) {
    float se = 0.f, so = 0.f;
#pragma unroll
    for (int q = 0; q <= 8; ++q) {   // even taps j=2q
      se += sa[2 * q] * Ew[t + q];
      so += sa[2 * q] * Ow[t + q];
    }
#pragma unroll
    for (int q = 0; q < 8; ++q) {    // odd taps j=2q+1
      se += sa[2 * q + 1] * Ow[t + q];
      so += sa[2 * q + 1] * Ew[t + q + 1];
    }
    res[2 * t]     = se + pb;
    res[2 * t + 1] = so + pb;
  }
  float* orow = out + (size_t)(b * 512 + e) * 8192 + 2 * lt;
  *(float4*)(orow)     = *(float4*)&res[0];
  *(float4*)(orow + 4) = *(float4*)&res[4];
}

// ---------------------------------------------------------------------------
extern "C" void kernel_launch(void* const* d_in, const int* in_sizes, int n_in,
                              void* d_out, int out_size, void* d_ws, size_t ws_size,
                              hipStream_t stream) {
  const float* x      = (const float*)d_in[0];
  const float* conv_w = (const float*)d_in[1];
  const float* conv_b = (const float*)d_in[2];
  const float* aa     = (const float*)d_in[3];
  const float* proj_w = (const float*)d_in[4];
  const float* proj_b = (const float*)d_in[5];
  float* out = (float*)d_out;

  char* ws = (char*)d_ws;
  __hip_bfloat16* Xt  = (__hip_bfloat16*)ws;                    // 33,554,432 B
  __hip_bfloat16* Mst = (__hip_bfloat16*)(ws + 33554432);       //  1,572,864 B
  float*          Pcb = (float*)(ws + 35127296);                //      2,048 B
  __hip_bfloat16* U   = (__hip_bfloat16*)(ws + 35129344);       // 100,663,296 B

  k_pre<<<dim3(4992, 1, 1), 256, 0, stream>>>(x, proj_w, conv_w, conv_b, Xt, Mst, Pcb);
  k_gemm<<<dim3(12, 256), 256, 0, stream>>>(Mst, Xt, Pcb, U);
  k_aa<<<dim3(4096, 4), 256, 0, stream>>>(U, aa, proj_b, out);
}

// Round 4
// 369.875 us; speedup vs baseline: 1.1176x; 1.0293x over previous
//
#include <hip/hip_runtime.h>
#include <hip/hip_bf16.h>

// Problem constants
#define BB_   8
#define DIM_  512
#define LIN_  4096
#define LOUT_ 8192

typedef __attribute__((ext_vector_type(8))) __bf16 bf16x8;
typedef __attribute__((ext_vector_type(4))) float  f32x4;
typedef __attribute__((ext_vector_type(8))) unsigned short u16x8;

__device__ __forceinline__ float bf2f(unsigned short u) {
  union { unsigned int i; float f; } x;
  x.i = ((unsigned int)u) << 16;
  return x.f;
}

// ---------------------------------------------------------------------------
// 1) k_prep: heterogeneous grid, 896 blocks.
//    [0,768):   Mstack[kk*512+e][i] = sum_d proj_w[e,d]*conv_w[d,i,kk] (bf16)
//    [768,896): Pcb[e] = sum_d proj_w[e,d]*conv_b[d]
__global__ __launch_bounds__(256) void k_prep(const float* __restrict__ proj_w,
                                              const float* __restrict__ conv_w,
                                              const float* __restrict__ conv_b,
                                              __hip_bfloat16* __restrict__ Mst,
                                              float* __restrict__ Pcb) {
  __shared__ float smem[2 * 32 * 33];
  const int bx  = blockIdx.x;
  const int tid = threadIdx.x;
  if (bx < 768) {
    const int kk = bx >> 8;
    const int et = ((bx >> 4) & 15) * 32;
    const int it = (bx & 15) * 32;
    float* Pt = smem;              // [32][33]
    float* Wt = smem + 32 * 33;    // [32][33]
    const int tx = tid & 15, ty = tid >> 4;
    float acc[2][2] = {};
    for (int d0 = 0; d0 < DIM_; d0 += 32) {
      {
        const int i = tid >> 3;
        const int j = (tid & 7) * 4;
        const float4 v = *(const float4*)&proj_w[(size_t)(et + i) * DIM_ + d0 + j];
        Pt[i * 33 + j] = v.x; Pt[i * 33 + j + 1] = v.y;
        Pt[i * 33 + j + 2] = v.z; Pt[i * 33 + j + 3] = v.w;
      }
#pragma unroll
      for (int r2 = 0; r2 < 4; ++r2) {
        const int id2 = tid + r2 * 256;
        const int i = id2 >> 5, j = id2 & 31;
        Wt[i * 33 + j] = conv_w[(size_t)(d0 + i) * (DIM_ * 3) + (it + j) * 3 + kk];
      }
      __syncthreads();
#pragma unroll
      for (int dl = 0; dl < 32; ++dl) {
        float pv[2], wv[2];
        pv[0] = Pt[(ty * 2) * 33 + dl];     pv[1] = Pt[(ty * 2 + 1) * 33 + dl];
        wv[0] = Wt[dl * 33 + tx * 2];       wv[1] = Wt[dl * 33 + tx * 2 + 1];
#pragma unroll
        for (int a = 0; a < 2; ++a)
#pragma unroll
          for (int bq = 0; bq < 2; ++bq) acc[a][bq] += pv[a] * wv[bq];
      }
      __syncthreads();
    }
#pragma unroll
    for (int a = 0; a < 2; ++a)
#pragma unroll
      for (int bq = 0; bq < 2; ++bq)
        Mst[(size_t)(kk * DIM_ + et + ty * 2 + a) * DIM_ + it + tx * 2 + bq] =
            __float2bfloat16(acc[a][bq]);
  } else {
    const int idx = bx - 768;
    const int e = idx * 4 + (tid >> 6);
    const int j = tid & 63;
    float s = 0.f;
#pragma unroll
    for (int d = j; d < DIM_; d += 64) s += proj_w[(size_t)e * DIM_ + d] * conv_b[d];
#pragma unroll
    for (int off = 32; off > 0; off >>= 1) s += __shfl_down(s, off, 64);
    if (j == 0) Pcb[e] = s;
  }
}

// ---------------------------------------------------------------------------
// 2) k_gemm, column-persistent: each block owns 64 output columns (one batch),
//    stages B = x[bb][:, l0..l0+64) ONCE (fp32->bf16, transposed+swizzled into
//    64KB LDS), then loops 12 row-tiles of A (Mstack, L2-resident) with a
//    BK=32 register-prefetch double buffer. U[kk][bb][e][l] bf16 out.
// grid 512 blocks x 256 threads; LDS 80KB -> 2 blocks/CU.
__global__ __launch_bounds__(256, 2) void k_gemm(const float* __restrict__ x,
                                                 const __hip_bfloat16* __restrict__ Mst,
                                                 const float* __restrict__ Pcb,
                                                 __hip_bfloat16* __restrict__ U) {
  __shared__ __align__(16) __hip_bfloat16 Bs[64 * 512];       // rows=l, 64 k-chunks of 8, swizzled
  __shared__ __align__(16) __hip_bfloat16 As[2][128 * 32];    // rows=m, 4 k-chunks of 8, swizzled
  const int tid = threadIdx.x;
  const int ct = blockIdx.x;
  const int bb = ct >> 6;
  const int l0 = (ct & 63) * 64;

  // ---- B-stage: read x coalesced (float4 along l), write LDS transposed ----
  {
    const float* xb = x + (size_t)bb * DIM_ * LIN_ + l0;
    const int dr = tid >> 4;             // 16 d-rows per pass
    const int lc = (tid & 15) * 4;       // 4 consecutive l per thread
#pragma unroll 4
    for (int p = 0; p < 32; ++p) {
      const int d = p * 16 + dr;
      const float4 v = *(const float4*)(xb + (size_t)d * LIN_ + lc);
      const int c8 = d >> 3, d7 = d & 7;
      const float vv[4] = {v.x, v.y, v.z, v.w};
#pragma unroll
      for (int j = 0; j < 4; ++j) {
        const int l = lc + j;
        Bs[l * 512 + ((c8 ^ (l & 7)) << 3) + d7] = __float2bfloat16(vv[j]);
      }
    }
  }

  // ---- A prologue: stage (rt=0, kt=0) ----
  const int r   = tid >> 2;              // 0..63; covers rows r and r+64
  const int chA = tid & 3;               // LDS slot
  const int swz = chA ^ (r & 3);         // global k-chunk feeding slot chA
  bf16x8 gA0 = *(const bf16x8*)(Mst + (size_t)r * 512 + swz * 8);
  bf16x8 gA1 = *(const bf16x8*)(Mst + (size_t)(r + 64) * 512 + swz * 8);
  *(bf16x8*)(&As[0][r * 32 + chA * 8]) = gA0;
  *(bf16x8*)(&As[0][(r + 64) * 32 + chA * 8]) = gA1;
  __syncthreads();

  const int lane = tid & 63;
  const int wave = tid >> 6;
  const int wm = wave >> 1, wn = wave & 1;      // wave tile: 64 rows x 32 cols
  const int kq = lane >> 4;                     // k-chunk within BK window
  const int mrow = wm * 64 + (lane & 15);
  const int slotA = kq ^ (lane & 3);            // = kq ^ (mrow&3), same for all mt
  const int lcol0 = wn * 32 + (lane & 15);

  f32x4 acc[4][2] = {};

  for (int it = 0; it < 192; ++it) {            // it = rt*16 + kt
    const int rt = it >> 4, kt = it & 15;
    const int cur = it & 1, nxt = cur ^ 1;

    if (it < 191) {                             // prefetch next BK window -> regs
      const int itn = it + 1;
      const int rtn = itn >> 4, ktn = itn & 15;
      const __hip_bfloat16* ap =
          Mst + (size_t)(rtn * 128 + r) * 512 + ktn * 32 + swz * 8;
      gA0 = *(const bf16x8*)(ap);
      gA1 = *(const bf16x8*)(ap + (size_t)64 * 512);
    }

    bf16x8 af[4], bfr[2];
#pragma unroll
    for (int mt = 0; mt < 4; ++mt)
      af[mt] = *(const bf16x8*)(&As[cur][(mrow + mt * 16) * 32 + slotA * 8]);
    const int ck = kt * 4 + kq;                 // global k-chunk 0..63
#pragma unroll
    for (int nt = 0; nt < 2; ++nt) {
      const int l = lcol0 + nt * 16;
      bfr[nt] = *(const bf16x8*)(&Bs[l * 512 + ((ck ^ (lane & 7)) << 3)]);
    }
#pragma unroll
    for (int mt = 0; mt < 4; ++mt)
#pragma unroll
      for (int nt = 0; nt < 2; ++nt)
        acc[mt][nt] = __builtin_amdgcn_mfma_f32_16x16x32_bf16(af[mt], bfr[nt],
                                                              acc[mt][nt], 0, 0, 0);

    if (it < 191) {                             // park prefetched tile in other buf
      *(bf16x8*)(&As[nxt][r * 32 + chA * 8]) = gA0;
      *(bf16x8*)(&As[nxt][(r + 64) * 32 + chA * 8]) = gA1;
    }

    if (kt == 15) {                             // row-tile epilogue
      const int kk = rt >> 2;                   // plane 0..2
      const int e0 = (rt & 3) * 128 + wm * 64;
#pragma unroll
      for (int mt = 0; mt < 4; ++mt) {
#pragma unroll
        for (int nt = 0; nt < 2; ++nt) {
          const int l = l0 + wn * 32 + nt * 16 + (lane & 15);   // D: col = lane&15
          const int ebase = e0 + mt * 16 + kq * 4;              // D: row = quad*4+reg
#pragma unroll
          for (int rr = 0; rr < 4; ++rr) {
            float v = acc[mt][nt][rr];
            const int e = ebase + rr;
            if (kk < 2) v += Pcb[e];            // bias exactly once across planes
            U[(size_t)((kk * 8 + bb) * 512 + e) * 4096 + l] = __float2bfloat16(v);
            acc[mt][nt][rr] = 0.f;
          }
        }
      }
    }
    __syncthreads();
  }
}

// ---------------------------------------------------------------------------
// 3) k_aa: AA filter + proj bias, barrier-free, 16B loads.
//    u_even(l) = U1[l];  u_odd(l) = U0[l] + U2[l+1] (zero-pad outside [0,4096))
//    out[2l+p] = 17-tap AA over u + proj_b[e]
// Thread: 8 consecutive l (16 outputs); 9 x u16x8 loads, 4 x float4 stores.
// grid (4096, 2), block 256
__global__ __launch_bounds__(256) void k_aa(const __hip_bfloat16* __restrict__ U,
                                            const float* __restrict__ aa,
                                            const float* __restrict__ proj_b,
                                            float* __restrict__ out) {
  const int b  = blockIdx.x >> 9;
  const int e  = blockIdx.x & 511;
  const int l0 = blockIdx.y << 11;
  const int tid = threadIdx.x;
  const int lt = l0 + 8 * tid;
  const unsigned short* q0 = (const unsigned short*)(U + (size_t)((0 * 8 + b) * 512 + e) * 4096);
  const unsigned short* q1 = (const unsigned short*)(U + (size_t)((1 * 8 + b) * 512 + e) * 4096);
  const unsigned short* q2 = (const unsigned short*)(U + (size_t)((2 * 8 + b) * 512 + e) * 4096);

  float E[17], O[16];                 // E[j]=u_even(lt-4+j), O[j]=u_odd(lt-4+j)
  if (lt >= 8 && lt + 16 <= 4096) {
    const int base = lt - 8;          // 16B aligned
    unsigned short r1[24], r0[24], r2[24];
#pragma unroll
    for (int c = 0; c < 3; ++c) {
      const u16x8 a = *(const u16x8*)(q1 + base + 8 * c);
      const u16x8 d = *(const u16x8*)(q0 + base + 8 * c);
      const u16x8 g = *(const u16x8*)(q2 + base + 8 * c);
#pragma unroll
      for (int j = 0; j < 8; ++j) {
        r1[8 * c + j] = a[j]; r0[8 * c + j] = d[j]; r2[8 * c + j] = g[j];
      }
    }
#pragma unroll
    for (int j = 0; j < 17; ++j) E[j] = bf2f(r1[4 + j]);
#pragma unroll
    for (int j = 0; j < 16; ++j) O[j] = bf2f(r0[4 + j]) + bf2f(r2[5 + j]);
  } else {
#pragma unroll
    for (int j = 0; j < 17; ++j) {
      const int l = lt - 4 + j;
      E[j] = (l >= 0 && l < 4096) ? bf2f(q1[l]) : 0.f;
    }
#pragma unroll
    for (int j = 0; j < 16; ++j) {
      const int l = lt - 4 + j;
      float v = 0.f;
      if (l >= 0 && l < 4096) {
        v = bf2f(q0[l]);
        if (l + 1 < 4096) v += bf2f(q2[l + 1]);
      }
      O[j] = v;
    }
  }

  float sa[17];
#pragma unroll
  for (int j = 0; j < 17; ++j) sa[j] = aa[j];
  const float pb = proj_b[e];
  float res[16];
#pragma unroll
  for (int t = 0; t < 8; ++t) {
    float se = 0.f, so = 0.f;
#pragma unroll
    for (int q = 0; q <= 8; ++q) {   // even taps j=2q
      se += sa[2 * q] * E[t + q];
      so += sa[2 * q] * O[t + q];
    }
#pragma unroll
    for (int q = 0; q < 8; ++q) {    // odd taps j=2q+1
      se += sa[2 * q + 1] * O[t + q];
      so += sa[2 * q + 1] * E[t + q + 1];
    }
    res[2 * t]     = se + pb;
    res[2 * t + 1] = so + pb;
  }
  float* orow = out + (size_t)(b * 512 + e) * 8192 + 2 * lt;
#pragma unroll
  for (int c = 0; c < 4; ++c)
    *(float4*)(orow + 4 * c) = *(const float4*)&res[4 * c];
}

// ---------------------------------------------------------------------------
extern "C" void kernel_launch(void* const* d_in, const int* in_sizes, int n_in,
                              void* d_out, int out_size, void* d_ws, size_t ws_size,
                              hipStream_t stream) {
  const float* x      = (const float*)d_in[0];
  const float* conv_w = (const float*)d_in[1];
  const float* conv_b = (const float*)d_in[2];
  const float* aa     = (const float*)d_in[3];
  const float* proj_w = (const float*)d_in[4];
  const float* proj_b = (const float*)d_in[5];
  float* out = (float*)d_out;

  char* ws = (char*)d_ws;
  __hip_bfloat16* Mst = (__hip_bfloat16*)ws;                 //  1,572,864 B
  float*          Pcb = (float*)(ws + 1572864);              //      2,048 B
  __hip_bfloat16* U   = (__hip_bfloat16*)(ws + 1576960);     // 100,663,296 B

  k_prep<<<dim3(896, 1, 1), 256, 0, stream>>>(proj_w, conv_w, conv_b, Mst, Pcb);
  k_gemm<<<dim3(512, 1, 1), 256, 0, stream>>>(x, Mst, Pcb, U);
  k_aa<<<dim3(4096, 2), 256, 0, stream>>>(U, aa, proj_b, out);
}